// Round 15
// baseline (86.978 us; speedup 1.0000x reference)
//
#include <hip/hip_runtime.h>
#include <hip/hip_bf16.h>

#define NN    4096
#define KNEI  16
#define QPW   8              // query nodes per wave (4 groups x 2 queries)
#define WPB   16             // waves per block
#define BLOCK (WPB * 64)
#define QPB   (WPB * QPW)    // 128 queries per block
#define NEGB  -3.0e38f
#define PACKM 0xFFFFFFC0

typedef float f32x2 __attribute__((ext_vector_type(2)));
typedef int   i32x2 __attribute__((ext_vector_type(2)));

__device__ __forceinline__ int rlane(int v, int l)
{ return __builtin_amdgcn_readlane(v, l); }
__device__ __forceinline__ float rlanef(float v, int l)
{ return __int_as_float(__builtin_amdgcn_readlane(__float_as_int(v), l)); }

template<int CTRL>
__device__ __forceinline__ float rmax_step(float f)
{
    int s_ = __builtin_amdgcn_update_dpp(__float_as_int(f), __float_as_int(f),
                                         CTRL, 0xF, 0xF, false);
    return fmaxf(f, __int_as_float(s_));
}

template<int CTRL>
__device__ __forceinline__ float radd_step(float f)
{
    int s_ = __builtin_amdgcn_update_dpp(__float_as_int(f), __float_as_int(f),
                                         CTRL, 0xF, 0xF, false);
    return f + __int_as_float(s_);
}

// rotate-reduce sum: EVERY lane of each 16-lane row ends with the row sum
__device__ __forceinline__ float row16_allsum(float v)
{
    v = radd_step<0x121>(v); v = radd_step<0x122>(v);
    v = radd_step<0x124>(v); v = radd_step<0x128>(v);
    return v;
}

// (f,i) joint argmax step — replay path only
template<int CTRL>
__device__ __forceinline__ void amax_step(float& f, int& i)
{
    int fs = __builtin_amdgcn_update_dpp(__float_as_int(f), __float_as_int(f),
                                         CTRL, 0xF, 0xF, false);
    int is = __builtin_amdgcn_update_dpp(i, i, CTRL, 0xF, 0xF, false);
    float ff = __int_as_float(fs);
    bool gt = ff > f;
    f = gt ? ff : f;
    i = gt ? is : i;
}

__device__ __forceinline__ void wave_amax(float f, int i, float& M, int& mi)
{
    amax_step<0x111>(f, i); amax_step<0x112>(f, i); amax_step<0x114>(f, i);
    amax_step<0x118>(f, i); amax_step<0x142>(f, i); amax_step<0x143>(f, i);
    M  = rlanef(f, 63);
    mi = rlane(i, 63);
}

__device__ __forceinline__ float bpermf(int abyte, float v)
{ return __int_as_float(__builtin_amdgcn_ds_bpermute(abyte, __float_as_int(v))); }

__device__ __forceinline__ float sel4f(float a, float b, float c, float d, int q)
{
    float lo = (q & 1) ? b : a;
    float hi = (q & 1) ? d : c;
    return (q & 2) ? hi : lo;
}

// purge self (always its column's packed max, possibly packed 2nd)
#define SELFFIX(q, b, s)                                                     \
    {  int cb_ = __float_as_int(b) & 63;                                     \
       if ((((cb_) << 6) | (lane ^ cb_)) == q0 + (q)) { (b) = (s); (s) = NEGB; } \
       int cs_ = __float_as_int(s) & 63;                                     \
       if ((((cs_) << 6) | (lane ^ cs_)) == q0 + (q)) { (s) = NEGB; } }

// rare wave-wide replay: rebuild diagonal colq's top-2 unselected members
__device__ __forceinline__ void replay_q(const float4* __restrict__ pts,
    const int* __restrict__ selp, int qLoc, float xq, float yq, float zq,
    unsigned long long exq, int colv, int kfv, int lane, int ownerBase,
    float& pb0, float& pb1, float& pb2, float& pb3,
    float& ps0, float& ps1, float& ps2, float& ps3)
{
    int wq = __ffsll((unsigned long long)exq) - 1;
    int colq = rlane(colv, wq);
    int kq   = rlane(kfv,  wq);
    int j2 = (lane << 6) | (colq ^ lane);
    float4 Pp = pts[j2];
    float scr = fmaf(Pp.x, xq, fmaf(Pp.y, yq, fmaf(Pp.z, zq, Pp.w)));
    float sf = __int_as_float((__float_as_int(scr) & PACKM) | lane);
    if (j2 == qLoc) sf = NEGB;
    const int4* sp = (const int4*)selp;
    int4 sa = sp[0], sb = sp[1], sc = sp[2], sd = sp[3];
    if (j2==sa.x || j2==sa.y || j2==sa.z || j2==sa.w) sf = NEGB;
    if (j2==sb.x || j2==sb.y || j2==sb.z || j2==sb.w) sf = NEGB;
    if (j2==sc.x || j2==sc.y || j2==sc.z || j2==sc.w) sf = NEGB;
    if (j2==sd.x || j2==sd.y || j2==sd.z || j2==sd.w) sf = NEGB;
    float M1; int i1;
    wave_amax(sf, j2, M1, i1);
    float sf2 = (j2 == i1) ? NEGB : sf;
    float M2; int i2;
    wave_amax(sf2, j2, M2, i2);
    bool ow = (lane == ownerBase + (colq & 15));
    if (kq == 0)      { pb0 = ow ? M1 : pb0; ps0 = ow ? M2 : ps0; }
    else if (kq == 1) { pb1 = ow ? M1 : pb1; ps1 = ow ? M2 : ps1; }
    else if (kq == 2) { pb2 = ow ? M1 : pb2; ps2 = ow ? M2 : ps2; }
    else              { pb3 = ow ? M1 : pb3; ps3 = ow ? M2 : ps3; }
}

// emit one query's 464-float output row using this 16-lane group (gt = lane&15)
__device__ __forceinline__ void emit_query(const float4* __restrict__ pts,
    const float* __restrict__ sW, const int* __restrict__ atypes,
    const int* __restrict__ rtypes, const float* __restrict__ aemb,
    const float* __restrict__ remb, float* __restrict__ out,
    int gq, int esel, float xq, float yq, float zq, int gt)
{
    float4 P = pts[esel];
    float rx = P.x - xq, ry = P.y - yq, rz = P.z - zq;   // sender - receiver
    float dist = sqrtf(rx*rx + ry*ry + rz*rz);
    float inv  = 1.0f / (dist + 1e-8f);
    float hx = rx * inv, hy = ry * inv, hz = rz * inv;
    float cu = fminf(dist / 10.0f, 1.0f);
    // g[v] = exp(-32(cu - v/7)^2) = A * E^v * K[v]
    float A = expf(cu * cu * -32.0f);
    float E = expf(cu * (64.0f / 7.0f));
    const float K[8] = {1.0f, 0.5204501f, 0.0733697f, 0.00280164f,
                        2.897772e-05f, 8.11857e-08f, 6.16130e-11f,
                        1.2664166e-14f};
    float gg[8];
    float t = A, ssum = A;
    gg[0] = A;
    #pragma unroll
    for (int v = 1; v < 8; ++v) { t *= E; gg[v] = t * K[v]; ssum += gg[v]; }
    float is = 1.0f / ssum;
    float S[24];
    #pragma unroll
    for (int v = 0; v < 8; ++v) {
        float rbv = gg[v] * is;
        S[3*v]   = rbv * hx;
        S[3*v+1] = rbv * hy;
        S[3*v+2] = rbv * hz;
    }
    #pragma unroll
    for (int t2 = 0; t2 < 24; ++t2) S[t2] = row16_allsum(S[t2]);

    float* onode = out + (size_t)gq * 464;
    float4* o4 = (float4*)onode;
    const float4 z4 = make_float4(0.f, 0.f, 0.f, 0.f);
    o4[gt] = z4;                        // ch 0..63
    o4[40 + gt] = z4;                   // ch 160..223
    if (gt < 4) o4[56 + gt] = z4;       // ch 224..239

    const float scale = 0.036084391824351613f;   // 1/(16*sqrt(3))
    float a0 = 0.f, a1 = 0.f, a2 = 0.f;          // w = gt
    float c0 = 0.f, c1 = 0.f, c2 = 0.f;          // w = gt + 16
    #pragma unroll
    for (int v = 0; v < 8; ++v) {
        float w0 = sW[32*v + gt];
        float w1 = sW[32*v + gt + 16];
        a0 = fmaf(w0, S[3*v],   a0);
        a1 = fmaf(w0, S[3*v+1], a1);
        a2 = fmaf(w0, S[3*v+2], a2);
        c0 = fmaf(w1, S[3*v],   c0);
        c1 = fmaf(w1, S[3*v+1], c1);
        c2 = fmaf(w1, S[3*v+2], c2);
    }
    onode[64 + 3*gt]          = a0 * scale;
    onode[64 + 3*gt + 1]      = a1 * scale;
    onode[64 + 3*gt + 2]      = a2 * scale;
    onode[64 + 3*(gt+16)]     = c0 * scale;
    onode[64 + 3*(gt+16) + 1] = c1 * scale;
    onode[64 + 3*(gt+16) + 2] = c2 * scale;

    const int at = atypes[gq];
    const int rt = rtypes[gq];
    #pragma unroll
    for (int rr = 0; rr < 4; ++rr) {
        int idx = gt + 16*rr;
        if (idx < 56) {
            float4 v = (idx < 28)
                ? ((const float4*)(aemb + 112*at))[idx]
                : ((const float4*)(remb + 112*rt))[idx - 28];
            o4[60 + idx] = v;
        }
    }
}

__global__ __launch_bounds__(BLOCK, 4)
void protein_enc_kernel(const float* __restrict__ coords,
                        const int*   __restrict__ atypes,
                        const int*   __restrict__ rtypes,
                        const float* __restrict__ tpw,
                        const float* __restrict__ aemb,
                        const float* __restrict__ remb,
                        float* __restrict__ out)
{
    __shared__ float4 pts[NN];          // 64 KB: x, y, z, -n2/2
    __shared__ float  sW[8 * 32];       // 1 KB
    __shared__ int    sel[WPB * 128];   // 8 KB: [wave][q(8)][r(16)]

    const int tid  = threadIdx.x;
    const int lane = tid & 63;
    const int wv   = tid >> 6;
    const int bpb  = NN / QPB;          // 32
    const int batch    = blockIdx.x / bpb;
    const int nodeBase = (blockIdx.x % bpb) * QPB;

    const float* cb = coords + (size_t)batch * NN * 3;

    for (int p = tid; p < NN; p += BLOCK) {
        float x = cb[3*p], y = cb[3*p+1], z = cb[3*p+2];
        pts[p] = make_float4(x, y, z, -0.5f * (x*x + y*y + z*z));
    }
    if (tid < 256) sW[tid] = tpw[tid];
    sel[wv*128 + lane] = -1;
    sel[wv*128 + 64 + lane] = -1;
    __syncthreads();

    const int q0 = nodeBase + wv * QPW;          // this wave's 8 query nodes
    const float4 Pq0 = pts[q0+0], Pq1 = pts[q0+1], Pq2 = pts[q0+2], Pq3 = pts[q0+3];
    const float4 Pq4 = pts[q0+4], Pq5 = pts[q0+5], Pq6 = pts[q0+6], Pq7 = pts[q0+7];
    const float x0=Pq0.x, y0=Pq0.y, z0=Pq0.z, x1=Pq1.x, y1=Pq1.y, z1=Pq1.z;
    const float x2=Pq2.x, y2=Pq2.y, z2=Pq2.z, x3=Pq3.x, y3=Pq3.y, z3=Pq3.z;
    const float x4=Pq4.x, y4=Pq4.y, z4v=Pq4.z, x5=Pq5.x, y5=Pq5.y, z5=Pq5.z;
    const float x6=Pq6.x, y6=Pq6.y, z6=Pq6.z, x7=Pq7.x, y7=Pq7.y, z7=Pq7.z;

    const f32x2 qx01={x0,x1}, qy01={y0,y1}, qz01={z0,z1};
    const f32x2 qx23={x2,x3}, qy23={y2,y3}, qz23={z2,z3};
    const f32x2 qx45={x4,x5}, qy45={y4,y5}, qz45={z4v,z5};
    const f32x2 qx67={x6,x7}, qy67={y6,y7}, qz67={z6,z7};
    const i32x2 MKv = {(int)PACKM, (int)PACKM};

    // ---- phase 1: diagonal scan; 8 packed top-2 ladders (4 pk pairs) ----
    f32x2 b01={NEGB,NEGB}, s01={NEGB,NEGB}, b23={NEGB,NEGB}, s23={NEGB,NEGB};
    f32x2 b45={NEGB,NEGB}, s45={NEGB,NEGB}, b67={NEGB,NEGB}, s67={NEGB,NEGB};

    #pragma unroll 8
    for (int c = 0; c < NN / 64; ++c) {
        int j = (c << 6) | (lane ^ c);
        float4 P = pts[j];
        f32x2 vx = {P.x, P.x}, vy = {P.y, P.y}, vz = {P.z, P.z}, vw = {P.w, P.w};
        f32x2 d01 = __builtin_elementwise_fma(vx, qx01,
                    __builtin_elementwise_fma(vy, qy01,
                    __builtin_elementwise_fma(vz, qz01, vw)));
        f32x2 d23 = __builtin_elementwise_fma(vx, qx23,
                    __builtin_elementwise_fma(vy, qy23,
                    __builtin_elementwise_fma(vz, qz23, vw)));
        f32x2 d45 = __builtin_elementwise_fma(vx, qx45,
                    __builtin_elementwise_fma(vy, qy45,
                    __builtin_elementwise_fma(vz, qz45, vw)));
        f32x2 d67 = __builtin_elementwise_fma(vx, qx67,
                    __builtin_elementwise_fma(vy, qy67,
                    __builtin_elementwise_fma(vz, qz67, vw)));
        i32x2 cc = {c, c};
        f32x2 p01 = __builtin_bit_cast(f32x2,(__builtin_bit_cast(i32x2,d01)&MKv)|cc);
        f32x2 p23 = __builtin_bit_cast(f32x2,(__builtin_bit_cast(i32x2,d23)&MKv)|cc);
        f32x2 p45 = __builtin_bit_cast(f32x2,(__builtin_bit_cast(i32x2,d45)&MKv)|cc);
        f32x2 p67 = __builtin_bit_cast(f32x2,(__builtin_bit_cast(i32x2,d67)&MKv)|cc);
        s01 = __builtin_elementwise_max(s01, __builtin_elementwise_min(p01, b01));
        b01 = __builtin_elementwise_max(b01, p01);
        s23 = __builtin_elementwise_max(s23, __builtin_elementwise_min(p23, b23));
        b23 = __builtin_elementwise_max(b23, p23);
        s45 = __builtin_elementwise_max(s45, __builtin_elementwise_min(p45, b45));
        b45 = __builtin_elementwise_max(b45, p45);
        s67 = __builtin_elementwise_max(s67, __builtin_elementwise_min(p67, b67));
        b67 = __builtin_elementwise_max(b67, p67);
    }

    float bb0=b01.x, bb1=b01.y, bb2=b23.x, bb3=b23.y;
    float bb4=b45.x, bb5=b45.y, bb6=b67.x, bb7=b67.y;
    float ss0=s01.x, ss1=s01.y, ss2=s23.x, ss3=s23.y;
    float ss4=s45.x, ss5=s45.y, ss6=s67.x, ss7=s67.y;

    SELFFIX(0, bb0, ss0) SELFFIX(1, bb1, ss1) SELFFIX(2, bb2, ss2)
    SELFFIX(3, bb3, ss3) SELFFIX(4, bb4, ss4) SELFFIX(5, bb5, ss5)
    SELFFIX(6, bb6, ss6) SELFFIX(7, bb7, ss7)

    // ---- redistribute: group g (16 lanes) gets queries 2g (A), 2g+1 (B);
    //      group-lane gt owns diagonals {gt, gt+16, gt+32, gt+48} ----
    const int g  = lane >> 4;
    const int gt = lane & 15;
    float pbA0,pbA1,pbA2,pbA3, psA0,psA1,psA2,psA3;
    float pbB0,pbB1,pbB2,pbB3, psB0,psB1,psB2,psB3;
#define PULL(K, PBA, PBB, PSA, PSB)                                          \
    {   int a = (gt + ((K) << 4)) << 2;                                      \
        float t0=bpermf(a,bb0), t1=bpermf(a,bb1), t2=bpermf(a,bb2),          \
              t3=bpermf(a,bb3), t4=bpermf(a,bb4), t5=bpermf(a,bb5),          \
              t6=bpermf(a,bb6), t7=bpermf(a,bb7);                            \
        PBA = sel4f(t0, t2, t4, t6, g);                                      \
        PBB = sel4f(t1, t3, t5, t7, g);                                      \
        float u0=bpermf(a,ss0), u1=bpermf(a,ss1), u2=bpermf(a,ss2),          \
              u3=bpermf(a,ss3), u4=bpermf(a,ss4), u5=bpermf(a,ss5),          \
              u6=bpermf(a,ss6), u7=bpermf(a,ss7);                            \
        PSA = sel4f(u0, u2, u4, u6, g);                                      \
        PSB = sel4f(u1, u3, u5, u7, g);                                      \
    }
    PULL(0, pbA0, pbB0, psA0, psB0)
    PULL(1, pbA1, pbB1, psA1, psB1)
    PULL(2, pbA2, pbB2, psA2, psB2)
    PULL(3, pbA3, pbB3, psA3, psB3)
#undef PULL

    // ---- phase 2: 16 rounds; each group extracts A and B concurrently ----
    const unsigned long long gmask = 0xFFFFull << (g << 4);
    int* selpA = &sel[wv*128 + (g << 5)];
    int* selpB = selpA + 16;

    #pragma unroll 1
    for (int r = 0; r < KNEI; ++r) {
        float fA = fmaxf(fmaxf(pbA0, pbA1), fmaxf(pbA2, pbA3));
        float fB = fmaxf(fmaxf(pbB0, pbB1), fmaxf(pbB2, pbB3));
        fA = rmax_step<0x121>(fA); fB = rmax_step<0x121>(fB);
        fA = rmax_step<0x122>(fA); fB = rmax_step<0x122>(fB);
        fA = rmax_step<0x124>(fA); fB = rmax_step<0x124>(fB);
        fA = rmax_step<0x128>(fA); fB = rmax_step<0x128>(fB);
        bool cA0=(pbA0==fA), cA1=(pbA1==fA), cA2=(pbA2==fA), cA3=(pbA3==fA);
        bool cB0=(pbB0==fB), cB1=(pbB1==fB), cB2=(pbB2==fB), cB3=(pbB3==fB);
        unsigned long long mA = __ballot(cA0|cA1|cA2|cA3);
        unsigned long long mB = __ballot(cB0|cB1|cB2|cB3);
        int wA = __ffsll(mA & gmask) - 1;
        int wB = __ffsll(mB & gmask) - 1;
        bool iwinA = (lane == wA), iwinB = (lane == wB);
        int kfA = cA0 ? 0 : (cA1 ? 1 : (cA2 ? 2 : 3));
        int kfB = cB0 ? 0 : (cB1 ? 1 : (cB2 ? 2 : 3));
        int cwA = __float_as_int(fA) & 63;
        int cwB = __float_as_int(fB) & 63;
        int colA = gt + (kfA << 4), colB = gt + (kfB << 4);
        int jA = (cwA << 6) | (colA ^ cwA);
        int jB = (cwB << 6) | (colB ^ cwB);
        if (iwinA) selpA[r] = jA;
        if (iwinB) selpB[r] = jB;
        bool oA0 = iwinA && cA0;
        bool oA1 = iwinA && !cA0 && cA1;
        bool oA2 = iwinA && !cA0 && !cA1 && cA2;
        bool oA3 = iwinA && !cA0 && !cA1 && !cA2;
        bool oB0 = iwinB && cB0;
        bool oB1 = iwinB && !cB0 && cB1;
        bool oB2 = iwinB && !cB0 && !cB1 && cB2;
        bool oB3 = iwinB && !cB0 && !cB1 && !cB2;
        float pskA = oA1 ? psA1 : (oA2 ? psA2 : (oA3 ? psA3 : psA0));
        float pskB = oB1 ? psB1 : (oB2 ? psB2 : (oB3 ? psB3 : psB0));
        bool eA = iwinA && (pskA == NEGB);
        bool eB = iwinB && (pskB == NEGB);
        pbA0 = oA0 ? psA0 : pbA0;  psA0 = oA0 ? NEGB : psA0;
        pbA1 = oA1 ? psA1 : pbA1;  psA1 = oA1 ? NEGB : psA1;
        pbA2 = oA2 ? psA2 : pbA2;  psA2 = oA2 ? NEGB : psA2;
        pbA3 = oA3 ? psA3 : pbA3;  psA3 = oA3 ? NEGB : psA3;
        pbB0 = oB0 ? psB0 : pbB0;  psB0 = oB0 ? NEGB : psB0;
        pbB1 = oB1 ? psB1 : pbB1;  psB1 = oB1 ? NEGB : psB1;
        pbB2 = oB2 ? psB2 : pbB2;  psB2 = oB2 ? NEGB : psB2;
        pbB3 = oB3 ? psB3 : pbB3;  psB3 = oB3 ? NEGB : psB3;
        unsigned long long exA = __ballot(eA);
        unsigned long long exB = __ballot(eB);
        if (exA | exB) {            // rare refill path
            if (exA & 0x000000000000FFFFull)
                replay_q(pts, &sel[wv*128+  0], q0+0, x0,y0,z0,
                         exA & 0x000000000000FFFFull, colA, kfA, lane, 0,
                         pbA0,pbA1,pbA2,pbA3, psA0,psA1,psA2,psA3);
            if (exB & 0x000000000000FFFFull)
                replay_q(pts, &sel[wv*128+ 16], q0+1, x1,y1,z1,
                         exB & 0x000000000000FFFFull, colB, kfB, lane, 0,
                         pbB0,pbB1,pbB2,pbB3, psB0,psB1,psB2,psB3);
            if (exA & 0x00000000FFFF0000ull)
                replay_q(pts, &sel[wv*128+ 32], q0+2, x2,y2,z2,
                         exA & 0x00000000FFFF0000ull, colA, kfA, lane, 16,
                         pbA0,pbA1,pbA2,pbA3, psA0,psA1,psA2,psA3);
            if (exB & 0x00000000FFFF0000ull)
                replay_q(pts, &sel[wv*128+ 48], q0+3, x3,y3,z3,
                         exB & 0x00000000FFFF0000ull, colB, kfB, lane, 16,
                         pbB0,pbB1,pbB2,pbB3, psB0,psB1,psB2,psB3);
            if (exA & 0x0000FFFF00000000ull)
                replay_q(pts, &sel[wv*128+ 64], q0+4, x4,y4,z4v,
                         exA & 0x0000FFFF00000000ull, colA, kfA, lane, 32,
                         pbA0,pbA1,pbA2,pbA3, psA0,psA1,psA2,psA3);
            if (exB & 0x0000FFFF00000000ull)
                replay_q(pts, &sel[wv*128+ 80], q0+5, x5,y5,z5,
                         exB & 0x0000FFFF00000000ull, colB, kfB, lane, 32,
                         pbB0,pbB1,pbB2,pbB3, psB0,psB1,psB2,psB3);
            if (exA & 0xFFFF000000000000ull)
                replay_q(pts, &sel[wv*128+ 96], q0+6, x6,y6,z6,
                         exA & 0xFFFF000000000000ull, colA, kfA, lane, 48,
                         pbA0,pbA1,pbA2,pbA3, psA0,psA1,psA2,psA3);
            if (exB & 0xFFFF000000000000ull)
                replay_q(pts, &sel[wv*128+112], q0+7, x7,y7,z7,
                         exB & 0xFFFF000000000000ull, colB, kfB, lane, 48,
                         pbB0,pbB1,pbB2,pbB3, psB0,psB1,psB2,psB3);
        }
    }

    // ---- epilogue: group g emits queries 2g and 2g+1 directly ----
    float xqA = sel4f(x0, x2, x4, x6, g);
    float yqA = sel4f(y0, y2, y4, y6, g);
    float zqA = sel4f(z0, z2, z4v, z6, g);
    float xqB = sel4f(x1, x3, x5, x7, g);
    float yqB = sel4f(y1, y3, y5, y7, g);
    float zqB = sel4f(z1, z3, z5, z7, g);

    int eselA = selpA[gt];
    int eselB = selpB[gt];
    int gqA = batch * NN + q0 + 2*g;

    emit_query(pts, sW, atypes, rtypes, aemb, remb, out,
               gqA,     eselA, xqA, yqA, zqA, gt);
    emit_query(pts, sW, atypes, rtypes, aemb, remb, out,
               gqA + 1, eselB, xqB, yqB, zqB, gt);
}

extern "C" void kernel_launch(void* const* d_in, const int* in_sizes, int n_in,
                              void* d_out, int out_size, void* d_ws, size_t ws_size,
                              hipStream_t stream)
{
    const float* coords = (const float*)d_in[0];
    const int*   at     = (const int*)  d_in[1];
    const int*   rt     = (const int*)  d_in[2];
    const float* tpw    = (const float*)d_in[3];
    const float* ae     = (const float*)d_in[4];
    const float* re     = (const float*)d_in[5];
    float* out = (float*)d_out;

    const int B = in_sizes[1] / NN;                  // 8
    dim3 grid(B * (NN / QPB));                       // 256
    protein_enc_kernel<<<grid, BLOCK, 0, stream>>>(coords, at, rt, tpw, ae, re, out);
}

// Round 16
// 82.675 us; speedup vs baseline: 1.0520x; 1.0520x over previous
//
#include <hip/hip_runtime.h>
#include <hip/hip_bf16.h>

#define NN    4096
#define KNEI  16
#define QPW   4              // query nodes per wave
#define WPB   16             // waves per block
#define BLOCK (WPB * 64)
#define QPB   (WPB * QPW)    // 64 queries per block
#define NEGB  -3.0e38f
#define PACKM 0xFFFFFFC0

typedef float f32x2 __attribute__((ext_vector_type(2)));
typedef int   i32x2 __attribute__((ext_vector_type(2)));

__device__ __forceinline__ int rlane(int v, int l)
{ return __builtin_amdgcn_readlane(v, l); }
__device__ __forceinline__ float rlanef(float v, int l)
{ return __int_as_float(__builtin_amdgcn_readlane(__float_as_int(v), l)); }

// f-only DPP max step (row_ror rotate-reduce)
template<int CTRL>
__device__ __forceinline__ float rmax_step(float f)
{
    int s_ = __builtin_amdgcn_update_dpp(__float_as_int(f), __float_as_int(f),
                                         CTRL, 0xF, 0xF, false);
    return fmaxf(f, __int_as_float(s_));
}

// (f,i) joint argmax step — replay path only
template<int CTRL>
__device__ __forceinline__ void amax_step(float& f, int& i)
{
    int fs = __builtin_amdgcn_update_dpp(__float_as_int(f), __float_as_int(f),
                                         CTRL, 0xF, 0xF, false);
    int is = __builtin_amdgcn_update_dpp(i, i, CTRL, 0xF, 0xF, false);
    float ff = __int_as_float(fs);
    bool gt = ff > f;
    f = gt ? ff : f;
    i = gt ? is : i;
}

__device__ __forceinline__ void wave_amax(float f, int i, float& M, int& mi)
{
    amax_step<0x111>(f, i); amax_step<0x112>(f, i); amax_step<0x114>(f, i);
    amax_step<0x118>(f, i); amax_step<0x142>(f, i); amax_step<0x143>(f, i);
    M  = rlanef(f, 63);
    mi = rlane(i, 63);
}

__device__ __forceinline__ float row16_sum_dpp(float v)  // lane 16r+15 -> row sum
{
    float f = v;
#define STEPA(CTRL)                                                          \
    { int s_ = __builtin_amdgcn_update_dpp(0, __float_as_int(f),             \
               (CTRL), 0xF, 0xF, true);                                      \
      f += __int_as_float(s_); }
    STEPA(0x111) STEPA(0x112) STEPA(0x114) STEPA(0x118)
#undef STEPA
    return f;
}

__device__ __forceinline__ float bpermf(int abyte, float v)
{ return __int_as_float(__builtin_amdgcn_ds_bpermute(abyte, __float_as_int(v))); }

__device__ __forceinline__ float sel4f(float a, float b, float c, float d, int q)
{
    float lo = (q & 1) ? b : a;
    float hi = (q & 1) ? d : c;
    return (q & 2) ? hi : lo;
}

// purge self (always its column's packed max, possibly packed 2nd)
#define SELFFIX(q, b, s)                                                     \
    {  int cb_ = __float_as_int(b) & 63;                                     \
       if ((((cb_) << 6) | (lane ^ cb_)) == q0 + (q)) { (b) = (s); (s) = NEGB; } \
       int cs_ = __float_as_int(s) & 63;                                     \
       if ((((cs_) << 6) | (lane ^ cs_)) == q0 + (q)) { (s) = NEGB; } }

// rare wave-wide replay: rebuild column colq's top-2 unselected members
#define REPLAY(qq, xq, yq, zq)                                               \
    {   int wq = __ffsll(ex & (0xFFFFull << ((qq) * 16))) - 1;               \
        int colq = rlane(col, wq);                                           \
        int kq   = rlane(kf,  wq);                                           \
        int j2 = (lane << 6) | (colq ^ lane);                                \
        float4 Pp = pts[j2];                                                 \
        float scr = fmaf(Pp.x,(xq), fmaf(Pp.y,(yq), fmaf(Pp.z,(zq), Pp.w))); \
        float sf = __int_as_float((__float_as_int(scr) & PACKM) | lane);     \
        if (j2 == q0 + (qq)) sf = NEGB;                                      \
        const int4* sp = (const int4*)&sel[wv * 64 + ((qq) << 4)];           \
        int4 sa = sp[0], sb = sp[1], sc = sp[2], sd = sp[3];                 \
        if (j2==sa.x || j2==sa.y || j2==sa.z || j2==sa.w) sf = NEGB;         \
        if (j2==sb.x || j2==sb.y || j2==sb.z || j2==sb.w) sf = NEGB;         \
        if (j2==sc.x || j2==sc.y || j2==sc.z || j2==sc.w) sf = NEGB;         \
        if (j2==sd.x || j2==sd.y || j2==sd.z || j2==sd.w) sf = NEGB;         \
        float M1; int i1;                                                    \
        wave_amax(sf, j2, M1, i1);                                           \
        float sf2 = (j2 == i1) ? NEGB : sf;                                  \
        float M2; int i2;                                                    \
        wave_amax(sf2, j2, M2, i2);                                          \
        bool ow = (lane == (qq) * 16 + (colq & 15));                         \
        if (kq == 0)      { pb0 = ow ? M1 : pb0; ps0 = ow ? M2 : ps0; }      \
        else if (kq == 1) { pb1 = ow ? M1 : pb1; ps1 = ow ? M2 : ps1; }      \
        else if (kq == 2) { pb2 = ow ? M1 : pb2; ps2 = ow ? M2 : ps2; }      \
        else              { pb3 = ow ? M1 : pb3; ps3 = ow ? M2 : ps3; }      \
    }

// 8 loads of diagonal candidates into a register buffer (constant-indexed)
#define LOAD8(BUF, CG)                                                       \
    _Pragma("unroll")                                                        \
    for (int u = 0; u < 8; ++u) {                                            \
        int c_ = (CG) * 8 + u;                                               \
        BUF[u] = pts[(c_ << 6) | (lane ^ c_)];                               \
    }

// 8 compute steps: packed scores + pk top-2 ladders for 4 queries
#define COMP8(BUF, CG)                                                       \
    _Pragma("unroll")                                                        \
    for (int u = 0; u < 8; ++u) {                                            \
        int c_ = (CG) * 8 + u;                                               \
        float4 P = BUF[u];                                                   \
        f32x2 vx = {P.x, P.x}, vy = {P.y, P.y};                              \
        f32x2 vz = {P.z, P.z}, vw = {P.w, P.w};                              \
        f32x2 dA = __builtin_elementwise_fma(vx, qAx,                        \
                   __builtin_elementwise_fma(vy, qAy,                        \
                   __builtin_elementwise_fma(vz, qAz, vw)));                 \
        f32x2 dB = __builtin_elementwise_fma(vx, qBx,                        \
                   __builtin_elementwise_fma(vy, qBy,                        \
                   __builtin_elementwise_fma(vz, qBz, vw)));                 \
        i32x2 cc = {c_, c_};                                                 \
        f32x2 pA = __builtin_bit_cast(f32x2,                                 \
                     (__builtin_bit_cast(i32x2, dA) & M2v) | cc);            \
        f32x2 pB = __builtin_bit_cast(f32x2,                                 \
                     (__builtin_bit_cast(i32x2, dB) & M2v) | cc);            \
        sA = __builtin_elementwise_max(sA, __builtin_elementwise_min(pA, bA)); \
        bA = __builtin_elementwise_max(bA, pA);                              \
        sB = __builtin_elementwise_max(sB, __builtin_elementwise_min(pB, bB)); \
        bB = __builtin_elementwise_max(bB, pB);                              \
    }

__global__ __launch_bounds__(BLOCK, 4)
void protein_enc_kernel(const float* __restrict__ coords,
                        const int*   __restrict__ atypes,
                        const int*   __restrict__ rtypes,
                        const float* __restrict__ tpw,
                        const float* __restrict__ aemb,
                        const float* __restrict__ remb,
                        float* __restrict__ out)
{
    __shared__ float4 pts[NN];          // 64 KB: x, y, z, -n2/2
    __shared__ float  sW[8 * 32];
    __shared__ int    sel[WPB * 64];    // 4 KB: [wave][q][r] selected indices

    const int tid  = threadIdx.x;
    const int lane = tid & 63;
    const int wv   = tid >> 6;
    const int bpb  = NN / QPB;
    const int batch    = blockIdx.x / bpb;
    const int nodeBase = (blockIdx.x % bpb) * QPB;

    const float* cb = coords + (size_t)batch * NN * 3;

    // ---- staging: contiguous float4 writes (conflict-free) ----
    for (int p = tid; p < NN; p += BLOCK) {
        float x = cb[3*p], y = cb[3*p+1], z = cb[3*p+2];
        pts[p] = make_float4(x, y, z, -0.5f * (x*x + y*y + z*z));
    }
    if (tid < 256) sW[tid] = tpw[tid];
    sel[wv * 64 + lane] = -1;           // wave-private init, no barrier needed
    __syncthreads();

    const int q0 = nodeBase + wv * QPW;          // this wave's 4 query nodes
    const float4 P0 = pts[q0],   P1 = pts[q0+1];
    const float4 P2 = pts[q0+2], P3 = pts[q0+3];
    const float x0 = P0.x, y0 = P0.y, z0 = P0.z;
    const float x1 = P1.x, y1 = P1.y, z1 = P1.z;
    const float x2 = P2.x, y2 = P2.y, z2 = P2.z;
    const float x3 = P3.x, y3 = P3.y, z3 = P3.z;

    const f32x2 qAx = {x0, x1}, qAy = {y0, y1}, qAz = {z0, z1};
    const f32x2 qBx = {x2, x3}, qBy = {y2, y3}, qBz = {z2, z3};
    const i32x2 M2v = {(int)PACKM, (int)PACKM};

    // ---- phase 1: diagonal scan, 8-deep double-buffered LDS prefetch ----
    f32x2 bA = {NEGB, NEGB}, sA = {NEGB, NEGB};
    f32x2 bB = {NEGB, NEGB}, sB = {NEGB, NEGB};

    {
        float4 Pa[8], Pb[8];
        LOAD8(Pa, 0)
        #pragma unroll 1
        for (int cg = 0; cg < 6; cg += 2) {
            LOAD8(Pb, cg + 1)
            COMP8(Pa, cg)
            LOAD8(Pa, cg + 2)
            COMP8(Pb, cg + 1)
        }
        LOAD8(Pb, 7)
        COMP8(Pa, 6)
        COMP8(Pb, 7)
    }

    float b0 = bA.x, b1 = bA.y, b2 = bB.x, b3 = bB.y;
    float s0 = sA.x, s1 = sA.y, s2 = sB.x, s3 = sB.y;

    SELFFIX(0, b0, s0)
    SELFFIX(1, b1, s1)
    SELFFIX(2, b2, s2)
    SELFFIX(3, b3, s3)

    // ---- redistribute: query q -> lanes 16q..16q+15; lane t owns columns
    //      {t, t+16, t+32, t+48} as slots 0..3 ----
    const int q  = lane >> 4;
    const int gt = lane & 15;
    float pb0, pb1, pb2, pb3, ps0, ps1, ps2, ps3;
    {
        const int ab = gt << 2;     // byte addr of source lane (column id)
#define PULL(K, PB, PS)                                                      \
        {   int a = ab + ((K) << 6);                                         \
            PB = sel4f(bpermf(a,b0), bpermf(a,b1), bpermf(a,b2), bpermf(a,b3), q); \
            PS = sel4f(bpermf(a,s0), bpermf(a,s1), bpermf(a,s2), bpermf(a,s3), q); \
        }
        PULL(0, pb0, ps0)
        PULL(1, pb1, ps1)
        PULL(2, pb2, ps2)
        PULL(3, pb3, ps3)
#undef PULL
    }

    // ---- phase 2: 16 rounds; f-only row reduce + owner-claim ----
    const unsigned long long gmask = 0xFFFFull << (q << 4);
    const int selbase = wv * 64 + (q << 4);

    #pragma unroll 1
    for (int r = 0; r < KNEI; ++r) {
        float f = fmaxf(fmaxf(pb0, pb1), fmaxf(pb2, pb3));
        f = rmax_step<0x121>(f); f = rmax_step<0x122>(f);
        f = rmax_step<0x124>(f); f = rmax_step<0x128>(f);
        // owner claim: bit-exact match against the row max
        bool c0 = (pb0 == f), c1 = (pb1 == f), c2 = (pb2 == f), c3 = (pb3 == f);
        unsigned long long m = __ballot(c0 | c1 | c2 | c3);
        int w = __ffsll(m & gmask) - 1;
        bool iwin = (lane == w);
        int kf = c0 ? 0 : (c1 ? 1 : (c2 ? 2 : 3));       // priority slot
        bool o0 = iwin && c0;
        bool o1 = iwin && !c0 && c1;
        bool o2 = iwin && !c0 && !c1 && c2;
        bool o3 = iwin && !c0 && !c1 && !c2;
        int cw  = __float_as_int(f) & 63;                // winner's row
        int col = gt + (kf << 4);                        // valid at owner
        int jw  = (cw << 6) | (col ^ cw);
        if (iwin) sel[selbase + r] = jw;
        float pskf = o1 ? ps1 : (o2 ? ps2 : (o3 ? ps3 : ps0));
        bool e = iwin && (pskf == NEGB);
        pb0 = o0 ? ps0 : pb0;  ps0 = o0 ? NEGB : ps0;
        pb1 = o1 ? ps1 : pb1;  ps1 = o1 ? NEGB : ps1;
        pb2 = o2 ? ps2 : pb2;  ps2 = o2 ? NEGB : ps2;
        pb3 = o3 ? ps3 : pb3;  ps3 = o3 ? NEGB : ps3;
        unsigned long long ex = __ballot(e);
        if (ex) {                                 // rare refill path
            if ((ex >>  0) & 0xFFFFull) REPLAY(0, x0, y0, z0)
            if ((ex >> 16) & 0xFFFFull) REPLAY(1, x1, y1, z1)
            if ((ex >> 32) & 0xFFFFull) REPLAY(2, x2, y2, z2)
            if ((ex >> 48) & 0xFFFFull) REPLAY(3, x3, y3, z3)
        }
    }

    // ---- epilogue: lane (16q+gt) owns edge gt of query q ----
    int selIdx = sel[wv * 64 + lane];

    float xq = (q & 2) ? ((q & 1) ? x3 : x2) : ((q & 1) ? x1 : x0);
    float yq = (q & 2) ? ((q & 1) ? y3 : y2) : ((q & 1) ? y1 : y0);
    float zq = (q & 2) ? ((q & 1) ? z3 : z2) : ((q & 1) ? z1 : z0);

    float4 P = pts[selIdx];
    float rx = P.x - xq, ry = P.y - yq, rz = P.z - zq;   // sender - receiver
    float dist = sqrtf(rx*rx + ry*ry + rz*rz);
    float inv  = 1.0f / (dist + 1e-8f);
    float hx = rx * inv, hy = ry * inv, hz = rz * inv;
    float cu = fminf(dist / 10.0f, 1.0f);
    // g[v] = exp(-32(cu - v/7)^2) = A * E^v * K[v];  2 expf instead of 8
    float A = expf(cu * cu * -32.0f);
    float E = expf(cu * (64.0f / 7.0f));
    const float K[8] = {1.0f, 0.5204501f, 0.0733697f, 0.00280164f,
                        2.897772e-05f, 8.11857e-08f, 6.16130e-11f,
                        1.2664166e-14f};
    float gg[8];
    float t = A, ssum = A;
    gg[0] = A;
    #pragma unroll
    for (int v = 1; v < 8; ++v) { t *= E; gg[v] = t * K[v]; ssum += gg[v]; }
    float is = 1.0f / ssum;
    float S[24];
    #pragma unroll
    for (int v = 0; v < 8; ++v) {
        float rbv = gg[v] * is;
        S[3*v]   = rbv * hx;
        S[3*v+1] = rbv * hy;
        S[3*v+2] = rbv * hz;
    }
    #pragma unroll
    for (int t2 = 0; t2 < 24; ++t2) S[t2] = row16_sum_dpp(S[t2]);

    float wcol[8];
    #pragma unroll
    for (int v = 0; v < 8; ++v) wcol[v] = sW[32*v + (lane & 31)];

    const float scale = 0.036084391824351613f;   // 1/(16*sqrt(3))
    const float4 z4 = make_float4(0.f, 0.f, 0.f, 0.f);

    #pragma unroll
    for (int qq = 0; qq < QPW; ++qq) {
        const int gq = batch * NN + q0 + qq;
        float sg[24];
        #pragma unroll
        for (int t2 = 0; t2 < 24; ++t2) sg[t2] = rlanef(S[t2], 16 * qq + 15);

        float* onode = out + (size_t)gq * 464;
        float4* o4 = (float4*)onode;
        if (lane < 16)       o4[lane] = z4;          // ch 0..63
        else if (lane < 36)  o4[lane + 24] = z4;     // ch 160..239

        if (lane < 32) {
            float a0 = 0.f, a1 = 0.f, a2 = 0.f;
            #pragma unroll
            for (int v = 0; v < 8; ++v) {
                a0 = fmaf(wcol[v], sg[3*v],   a0);
                a1 = fmaf(wcol[v], sg[3*v+1], a1);
                a2 = fmaf(wcol[v], sg[3*v+2], a2);
            }
            onode[64 + 3*lane]     = a0 * scale;
            onode[64 + 3*lane + 1] = a1 * scale;
            onode[64 + 3*lane + 2] = a2 * scale;
        }

        const int at = atypes[gq];
        const int rt = rtypes[gq];
        if (lane < 56) {
            float4 v = (lane < 28)
                ? ((const float4*)(aemb + 112*at))[lane]
                : ((const float4*)(remb + 112*rt))[lane - 28];
            o4[60 + lane] = v;
        }
    }
}

extern "C" void kernel_launch(void* const* d_in, const int* in_sizes, int n_in,
                              void* d_out, int out_size, void* d_ws, size_t ws_size,
                              hipStream_t stream)
{
    const float* coords = (const float*)d_in[0];
    const int*   at     = (const int*)  d_in[1];
    const int*   rt     = (const int*)  d_in[2];
    const float* tpw    = (const float*)d_in[3];
    const float* ae     = (const float*)d_in[4];
    const float* re     = (const float*)d_in[5];
    float* out = (float*)d_out;

    const int B = in_sizes[1] / NN;                  // 8
    dim3 grid(B * (NN / QPB));
    protein_enc_kernel<<<grid, BLOCK, 0, stream>>>(coords, at, rt, tpw, ae, re, out);
}

// Round 17
// 73.114 us; speedup vs baseline: 1.1896x; 1.1308x over previous
//
#include <hip/hip_runtime.h>
#include <hip/hip_bf16.h>

#define NN    4096
#define KNEI  16
#define QPW   4              // query nodes per wave
#define WPB   16             // waves per block
#define BLOCK (WPB * 64)
#define QPB   (WPB * QPW)    // 64 queries per block
#define NEGB  -3.0e38f
#define PACKM 0xFFFFFFC0

typedef float f32x2 __attribute__((ext_vector_type(2)));
typedef int   i32x2 __attribute__((ext_vector_type(2)));

__device__ __forceinline__ int rlane(int v, int l)
{ return __builtin_amdgcn_readlane(v, l); }
__device__ __forceinline__ float rlanef(float v, int l)
{ return __int_as_float(__builtin_amdgcn_readlane(__float_as_int(v), l)); }

// f-only DPP max step (row_ror rotate-reduce)
template<int CTRL>
__device__ __forceinline__ float rmax_step(float f)
{
    int s_ = __builtin_amdgcn_update_dpp(__float_as_int(f), __float_as_int(f),
                                         CTRL, 0xF, 0xF, false);
    return fmaxf(f, __int_as_float(s_));
}

// (f,i) joint argmax step — replay path only
template<int CTRL>
__device__ __forceinline__ void amax_step(float& f, int& i)
{
    int fs = __builtin_amdgcn_update_dpp(__float_as_int(f), __float_as_int(f),
                                         CTRL, 0xF, 0xF, false);
    int is = __builtin_amdgcn_update_dpp(i, i, CTRL, 0xF, 0xF, false);
    float ff = __int_as_float(fs);
    bool gt = ff > f;
    f = gt ? ff : f;
    i = gt ? is : i;
}

__device__ __forceinline__ void wave_amax(float f, int i, float& M, int& mi)
{
    amax_step<0x111>(f, i); amax_step<0x112>(f, i); amax_step<0x114>(f, i);
    amax_step<0x118>(f, i); amax_step<0x142>(f, i); amax_step<0x143>(f, i);
    M  = rlanef(f, 63);
    mi = rlane(i, 63);
}

__device__ __forceinline__ float row16_sum_dpp(float v)  // lane 16r+15 -> row sum
{
    float f = v;
#define STEPA(CTRL)                                                          \
    { int s_ = __builtin_amdgcn_update_dpp(0, __float_as_int(f),             \
               (CTRL), 0xF, 0xF, true);                                      \
      f += __int_as_float(s_); }
    STEPA(0x111) STEPA(0x112) STEPA(0x114) STEPA(0x118)
#undef STEPA
    return f;
}

__device__ __forceinline__ float bpermf(int abyte, float v)
{ return __int_as_float(__builtin_amdgcn_ds_bpermute(abyte, __float_as_int(v))); }

__device__ __forceinline__ float sel4f(float a, float b, float c, float d, int q)
{
    float lo = (q & 1) ? b : a;
    float hi = (q & 1) ? d : c;
    return (q & 2) ? hi : lo;
}

// purge self (always its column's packed max, possibly packed 2nd)
#define SELFFIX(q, b, s)                                                     \
    {  int cb_ = __float_as_int(b) & 63;                                     \
       if ((((cb_) << 6) | (lane ^ cb_)) == q0 + (q)) { (b) = (s); (s) = NEGB; } \
       int cs_ = __float_as_int(s) & 63;                                     \
       if ((((cs_) << 6) | (lane ^ cs_)) == q0 + (q)) { (s) = NEGB; } }

// rare wave-wide replay: rebuild column colq's top-2 unselected members
#define REPLAY(qq, xq, yq, zq)                                               \
    {   int wq = __ffsll(ex & (0xFFFFull << ((qq) * 16))) - 1;               \
        int colq = rlane(col, wq);                                           \
        int kq   = rlane(kf,  wq);                                           \
        int j2 = (lane << 6) | (colq ^ lane);                                \
        float4 Pp = pts[j2];                                                 \
        float scr = fmaf(Pp.x,(xq), fmaf(Pp.y,(yq), fmaf(Pp.z,(zq), Pp.w))); \
        float sf = __int_as_float((__float_as_int(scr) & PACKM) | lane);     \
        if (j2 == q0 + (qq)) sf = NEGB;                                      \
        const int4* sp = (const int4*)&sel[wv * 64 + ((qq) << 4)];           \
        int4 sa = sp[0], sb = sp[1], sc = sp[2], sd = sp[3];                 \
        if (j2==sa.x || j2==sa.y || j2==sa.z || j2==sa.w) sf = NEGB;         \
        if (j2==sb.x || j2==sb.y || j2==sb.z || j2==sb.w) sf = NEGB;         \
        if (j2==sc.x || j2==sc.y || j2==sc.z || j2==sc.w) sf = NEGB;         \
        if (j2==sd.x || j2==sd.y || j2==sd.z || j2==sd.w) sf = NEGB;         \
        float M1; int i1;                                                    \
        wave_amax(sf, j2, M1, i1);                                           \
        float sf2 = (j2 == i1) ? NEGB : sf;                                  \
        float M2; int i2;                                                    \
        wave_amax(sf2, j2, M2, i2);                                          \
        bool ow = (lane == (qq) * 16 + (colq & 15));                         \
        if (kq == 0)      { pb0 = ow ? M1 : pb0; ps0 = ow ? M2 : ps0; }      \
        else if (kq == 1) { pb1 = ow ? M1 : pb1; ps1 = ow ? M2 : ps1; }      \
        else if (kq == 2) { pb2 = ow ? M1 : pb2; ps2 = ow ? M2 : ps2; }      \
        else              { pb3 = ow ? M1 : pb3; ps3 = ow ? M2 : ps3; }      \
    }

// 4 loads of diagonal candidates into a register buffer (constant-indexed)
#define LOAD4(BUF, CG)                                                       \
    _Pragma("unroll")                                                        \
    for (int u = 0; u < 4; ++u) {                                            \
        int c_ = (CG) * 4 + u;                                               \
        BUF[u] = pts[(c_ << 6) | (lane ^ c_)];                               \
    }

// 4 compute steps: packed scores + pk top-2 ladders for 4 queries
#define COMP4(BUF, CG)                                                       \
    _Pragma("unroll")                                                        \
    for (int u = 0; u < 4; ++u) {                                            \
        int c_ = (CG) * 4 + u;                                               \
        float4 P = BUF[u];                                                   \
        f32x2 vx = {P.x, P.x}, vy = {P.y, P.y};                              \
        f32x2 vz = {P.z, P.z}, vw = {P.w, P.w};                              \
        f32x2 dA = __builtin_elementwise_fma(vx, qAx,                        \
                   __builtin_elementwise_fma(vy, qAy,                        \
                   __builtin_elementwise_fma(vz, qAz, vw)));                 \
        f32x2 dB = __builtin_elementwise_fma(vx, qBx,                        \
                   __builtin_elementwise_fma(vy, qBy,                        \
                   __builtin_elementwise_fma(vz, qBz, vw)));                 \
        i32x2 cc = {c_, c_};                                                 \
        f32x2 pA = __builtin_bit_cast(f32x2,                                 \
                     (__builtin_bit_cast(i32x2, dA) & M2v) | cc);            \
        f32x2 pB = __builtin_bit_cast(f32x2,                                 \
                     (__builtin_bit_cast(i32x2, dB) & M2v) | cc);            \
        sA = __builtin_elementwise_max(sA, __builtin_elementwise_min(pA, bA)); \
        bA = __builtin_elementwise_max(bA, pA);                              \
        sB = __builtin_elementwise_max(sB, __builtin_elementwise_min(pB, bB)); \
        bB = __builtin_elementwise_max(bB, pB);                              \
    }

__global__ __launch_bounds__(BLOCK, 8)
void protein_enc_kernel(const float* __restrict__ coords,
                        const int*   __restrict__ atypes,
                        const int*   __restrict__ rtypes,
                        const float* __restrict__ tpw,
                        const float* __restrict__ aemb,
                        const float* __restrict__ remb,
                        float* __restrict__ out)
{
    __shared__ float4 pts[NN];          // 64 KB: x, y, z, -n2/2
    __shared__ float  sW[8 * 32];
    __shared__ int    sel[WPB * 64];    // 4 KB: [wave][q][r] selected indices

    const int tid  = threadIdx.x;
    const int lane = tid & 63;
    const int wv   = tid >> 6;
    const int bpb  = NN / QPB;
    const int batch    = blockIdx.x / bpb;
    const int nodeBase = (blockIdx.x % bpb) * QPB;

    const float* cb = coords + (size_t)batch * NN * 3;

    // ---- staging: contiguous float4 writes (conflict-free) ----
    for (int p = tid; p < NN; p += BLOCK) {
        float x = cb[3*p], y = cb[3*p+1], z = cb[3*p+2];
        pts[p] = make_float4(x, y, z, -0.5f * (x*x + y*y + z*z));
    }
    if (tid < 256) sW[tid] = tpw[tid];
    sel[wv * 64 + lane] = -1;           // wave-private init, no barrier needed
    __syncthreads();

    const int q0 = nodeBase + wv * QPW;          // this wave's 4 query nodes
    const float4 P0 = pts[q0],   P1 = pts[q0+1];
    const float4 P2 = pts[q0+2], P3 = pts[q0+3];
    const float x0 = P0.x, y0 = P0.y, z0 = P0.z;
    const float x1 = P1.x, y1 = P1.y, z1 = P1.z;
    const float x2 = P2.x, y2 = P2.y, z2 = P2.z;
    const float x3 = P3.x, y3 = P3.y, z3 = P3.z;

    const f32x2 qAx = {x0, x1}, qAy = {y0, y1}, qAz = {z0, z1};
    const f32x2 qBx = {x2, x3}, qBy = {y2, y3}, qBz = {z2, z3};
    const i32x2 M2v = {(int)PACKM, (int)PACKM};

    // ---- phase 1: diagonal scan; 4-deep double-buffered LDS pipeline
    //      under the 64-VGPR budget (keeps 8 waves/SIMD residency) ----
    f32x2 bA = {NEGB, NEGB}, sA = {NEGB, NEGB};
    f32x2 bB = {NEGB, NEGB}, sB = {NEGB, NEGB};

    {
        float4 Qa[4], Qb[4];
        LOAD4(Qa, 0)
        #pragma unroll 1
        for (int cg = 0; cg < 14; cg += 2) {
            LOAD4(Qb, cg + 1)
            COMP4(Qa, cg)
            LOAD4(Qa, cg + 2)
            COMP4(Qb, cg + 1)
        }
        LOAD4(Qb, 15)
        COMP4(Qa, 14)
        COMP4(Qb, 15)
    }

    float b0 = bA.x, b1 = bA.y, b2 = bB.x, b3 = bB.y;
    float s0 = sA.x, s1 = sA.y, s2 = sB.x, s3 = sB.y;

    SELFFIX(0, b0, s0)
    SELFFIX(1, b1, s1)
    SELFFIX(2, b2, s2)
    SELFFIX(3, b3, s3)

    // ---- redistribute: query q -> lanes 16q..16q+15; lane t owns columns
    //      {t, t+16, t+32, t+48} as slots 0..3 ----
    const int q  = lane >> 4;
    const int gt = lane & 15;
    float pb0, pb1, pb2, pb3, ps0, ps1, ps2, ps3;
    {
        const int ab = gt << 2;     // byte addr of source lane (column id)
#define PULL(K, PB, PS)                                                      \
        {   int a = ab + ((K) << 6);                                         \
            PB = sel4f(bpermf(a,b0), bpermf(a,b1), bpermf(a,b2), bpermf(a,b3), q); \
            PS = sel4f(bpermf(a,s0), bpermf(a,s1), bpermf(a,s2), bpermf(a,s3), q); \
        }
        PULL(0, pb0, ps0)
        PULL(1, pb1, ps1)
        PULL(2, pb2, ps2)
        PULL(3, pb3, ps3)
#undef PULL
    }

    // ---- phase 2: 16 rounds; f-only row reduce + owner-claim ----
    const unsigned long long gmask = 0xFFFFull << (q << 4);
    const int selbase = wv * 64 + (q << 4);

    #pragma unroll 1
    for (int r = 0; r < KNEI; ++r) {
        float f = fmaxf(fmaxf(pb0, pb1), fmaxf(pb2, pb3));
        f = rmax_step<0x121>(f); f = rmax_step<0x122>(f);
        f = rmax_step<0x124>(f); f = rmax_step<0x128>(f);
        // owner claim: bit-exact match against the row max
        bool c0 = (pb0 == f), c1 = (pb1 == f), c2 = (pb2 == f), c3 = (pb3 == f);
        unsigned long long m = __ballot(c0 | c1 | c2 | c3);
        int w = __ffsll(m & gmask) - 1;
        bool iwin = (lane == w);
        int kf = c0 ? 0 : (c1 ? 1 : (c2 ? 2 : 3));       // priority slot
        bool o0 = iwin && c0;
        bool o1 = iwin && !c0 && c1;
        bool o2 = iwin && !c0 && !c1 && c2;
        bool o3 = iwin && !c0 && !c1 && !c2;
        int cw  = __float_as_int(f) & 63;                // winner's row
        int col = gt + (kf << 4);                        // valid at owner
        int jw  = (cw << 6) | (col ^ cw);
        if (iwin) sel[selbase + r] = jw;
        float pskf = o1 ? ps1 : (o2 ? ps2 : (o3 ? ps3 : ps0));
        bool e = iwin && (pskf == NEGB);
        pb0 = o0 ? ps0 : pb0;  ps0 = o0 ? NEGB : ps0;
        pb1 = o1 ? ps1 : pb1;  ps1 = o1 ? NEGB : ps1;
        pb2 = o2 ? ps2 : pb2;  ps2 = o2 ? NEGB : ps2;
        pb3 = o3 ? ps3 : pb3;  ps3 = o3 ? NEGB : ps3;
        unsigned long long ex = __ballot(e);
        if (ex) {                                 // rare refill path
            if ((ex >>  0) & 0xFFFFull) REPLAY(0, x0, y0, z0)
            if ((ex >> 16) & 0xFFFFull) REPLAY(1, x1, y1, z1)
            if ((ex >> 32) & 0xFFFFull) REPLAY(2, x2, y2, z2)
            if ((ex >> 48) & 0xFFFFull) REPLAY(3, x3, y3, z3)
        }
    }

    // ---- epilogue: lane (16q+gt) owns edge gt of query q ----
    int selIdx = sel[wv * 64 + lane];

    float xq = (q & 2) ? ((q & 1) ? x3 : x2) : ((q & 1) ? x1 : x0);
    float yq = (q & 2) ? ((q & 1) ? y3 : y2) : ((q & 1) ? y1 : y0);
    float zq = (q & 2) ? ((q & 1) ? z3 : z2) : ((q & 1) ? z1 : z0);

    float4 P = pts[selIdx];
    float rx = P.x - xq, ry = P.y - yq, rz = P.z - zq;   // sender - receiver
    float dist = sqrtf(rx*rx + ry*ry + rz*rz);
    float inv  = 1.0f / (dist + 1e-8f);
    float hx = rx * inv, hy = ry * inv, hz = rz * inv;
    float cu = fminf(dist / 10.0f, 1.0f);
    // g[v] = exp(-32(cu - v/7)^2) = A * E^v * K[v];  2 expf instead of 8
    float A = expf(cu * cu * -32.0f);
    float E = expf(cu * (64.0f / 7.0f));
    const float K[8] = {1.0f, 0.5204501f, 0.0733697f, 0.00280164f,
                        2.897772e-05f, 8.11857e-08f, 6.16130e-11f,
                        1.2664166e-14f};
    float gg[8];
    float t = A, ssum = A;
    gg[0] = A;
    #pragma unroll
    for (int v = 1; v < 8; ++v) { t *= E; gg[v] = t * K[v]; ssum += gg[v]; }
    float is = 1.0f / ssum;
    float S[24];
    #pragma unroll
    for (int v = 0; v < 8; ++v) {
        float rbv = gg[v] * is;
        S[3*v]   = rbv * hx;
        S[3*v+1] = rbv * hy;
        S[3*v+2] = rbv * hz;
    }
    #pragma unroll
    for (int t2 = 0; t2 < 24; ++t2) S[t2] = row16_sum_dpp(S[t2]);

    float wcol[8];
    #pragma unroll
    for (int v = 0; v < 8; ++v) wcol[v] = sW[32*v + (lane & 31)];

    const float scale = 0.036084391824351613f;   // 1/(16*sqrt(3))
    const float4 z4 = make_float4(0.f, 0.f, 0.f, 0.f);

    #pragma unroll
    for (int qq = 0; qq < QPW; ++qq) {
        const int gq = batch * NN + q0 + qq;
        float sg[24];
        #pragma unroll
        for (int t2 = 0; t2 < 24; ++t2) sg[t2] = rlanef(S[t2], 16 * qq + 15);

        float* onode = out + (size_t)gq * 464;
        float4* o4 = (float4*)onode;
        if (lane < 16)       o4[lane] = z4;          // ch 0..63
        else if (lane < 36)  o4[lane + 24] = z4;     // ch 160..239

        if (lane < 32) {
            float a0 = 0.f, a1 = 0.f, a2 = 0.f;
            #pragma unroll
            for (int v = 0; v < 8; ++v) {
                a0 = fmaf(wcol[v], sg[3*v],   a0);
                a1 = fmaf(wcol[v], sg[3*v+1], a1);
                a2 = fmaf(wcol[v], sg[3*v+2], a2);
            }
            onode[64 + 3*lane]     = a0 * scale;
            onode[64 + 3*lane + 1] = a1 * scale;
            onode[64 + 3*lane + 2] = a2 * scale;
        }

        const int at = atypes[gq];
        const int rt = rtypes[gq];
        if (lane < 56) {
            float4 v = (lane < 28)
                ? ((const float4*)(aemb + 112*at))[lane]
                : ((const float4*)(remb + 112*rt))[lane - 28];
            o4[60 + lane] = v;
        }
    }
}

extern "C" void kernel_launch(void* const* d_in, const int* in_sizes, int n_in,
                              void* d_out, int out_size, void* d_ws, size_t ws_size,
                              hipStream_t stream)
{
    const float* coords = (const float*)d_in[0];
    const int*   at     = (const int*)  d_in[1];
    const int*   rt     = (const int*)  d_in[2];
    const float* tpw    = (const float*)d_in[3];
    const float* ae     = (const float*)d_in[4];
    const float* re     = (const float*)d_in[5];
    float* out = (float*)d_out;

    const int B = in_sizes[1] / NN;                  // 8
    dim3 grid(B * (NN / QPB));
    protein_enc_kernel<<<grid, BLOCK, 0, stream>>>(coords, at, rt, tpw, ae, re, out);
}